// Round 3
// baseline (175.156 us; speedup 1.0000x reference)
//
#include <hip/hip_runtime.h>

#define NROWS 4096
#define DDIM  256
#define MARGIN 0.1f

typedef __attribute__((ext_vector_type(4)))  _Float16 half4;
typedef __attribute__((ext_vector_type(8)))  _Float16 half8;
typedef __attribute__((ext_vector_type(16))) float    floatx16;

// ================= PATH A: pre-converted hi/lo, LDS-free MFMA =================

// ---- Kernel A1: fp32 -> (hi,lo) f16 split arrays + diag + zero accumulators ----
__global__ __launch_bounds__(256) void convert_diag_kernel(
    const float* __restrict__ v, const float* __restrict__ t,
    _Float16* __restrict__ vhi, _Float16* __restrict__ vlo,
    _Float16* __restrict__ thi, _Float16* __restrict__ tlo,
    float* __restrict__ diag, int* __restrict__ rank, float* __restrict__ sums) {
  const int w    = threadIdx.x >> 6;
  const int lane = threadIdx.x & 63;
  const int row  = blockIdx.x * 4 + w;
  const size_t base = (size_t)row * DDIM;
  const float4 a = ((const float4*)(v + base))[lane];
  const float4 b = ((const float4*)(t + base))[lane];
  half4 ah, al, bh, bl;
  ah.x = (_Float16)a.x; al.x = (_Float16)(a.x - (float)ah.x);
  ah.y = (_Float16)a.y; al.y = (_Float16)(a.y - (float)ah.y);
  ah.z = (_Float16)a.z; al.z = (_Float16)(a.z - (float)ah.z);
  ah.w = (_Float16)a.w; al.w = (_Float16)(a.w - (float)ah.w);
  bh.x = (_Float16)b.x; bl.x = (_Float16)(b.x - (float)bh.x);
  bh.y = (_Float16)b.y; bl.y = (_Float16)(b.y - (float)bh.y);
  bh.z = (_Float16)b.z; bl.z = (_Float16)(b.z - (float)bh.z);
  bh.w = (_Float16)b.w; bl.w = (_Float16)(b.w - (float)bh.w);
  ((half4*)(vhi + base))[lane] = ah;
  ((half4*)(vlo + base))[lane] = al;
  ((half4*)(thi + base))[lane] = bh;
  ((half4*)(tlo + base))[lane] = bl;
  float s = a.x*b.x + a.y*b.y + a.z*b.z + a.w*b.w;
  #pragma unroll
  for (int off = 32; off; off >>= 1) s += __shfl_down(s, off);
  if (lane == 0) { diag[row] = s; rank[row] = 0; }
  if (blockIdx.x == 0 && threadIdx.x < 2) sums[threadIdx.x] = 0.f;
}

// ---- Kernel A2: barrier-free MFMA GEMM + fused epilogue ----
// 512 blocks, 4 waves each; block tile 256(i) x 128(j); wave tile 128x64.
// Fragments loaded straight from global (L2-resident), double-buffered regs.
__global__ __launch_bounds__(256, 2) void main_mfma(
    const _Float16* __restrict__ vhi, const _Float16* __restrict__ vlo,
    const _Float16* __restrict__ thi, const _Float16* __restrict__ tlo,
    const float* __restrict__ diag, float* __restrict__ sums,
    int* __restrict__ rank) {
  __shared__ float sdi[256];
  __shared__ float sdj[128];

  const int tid  = threadIdx.x;
  const int w    = tid >> 6;
  const int lane = tid & 63;

  // XCD-aware swizzle: id&7 = XCD (heuristic); each XCD covers 2 i-slabs x 32 j.
  const int id  = blockIdx.x;
  const int xcd = id & 7;
  const int lp  = id >> 3;
  const int i0  = (xcd * 2 + (lp >> 5)) * 256;
  const int j0  = (lp & 31) * 128;
  const int iw  = i0 + (w >> 1) * 128;
  const int jw  = j0 + (w & 1) * 64;

  const int row = lane & 31;
  const int kh  = (lane >> 5) * 8;

  int offA[4], offB[2];   // element offsets, shared by hi/lo arrays
  #pragma unroll
  for (int mt = 0; mt < 4; ++mt) offA[mt] = (iw + mt * 32 + row) * DDIM + kh;
  #pragma unroll
  for (int nt = 0; nt < 2; ++nt) offB[nt] = (jw + nt * 32 + row) * DDIM + kh;

  floatx16 acc[4][2];
  #pragma unroll
  for (int mt = 0; mt < 4; ++mt)
    #pragma unroll
    for (int nt = 0; nt < 2; ++nt)
      #pragma unroll
      for (int r = 0; r < 16; ++r) acc[mt][nt][r] = 0.f;

  half8 Ah[2][4], Al[2][4], Bh[2][2], Bl[2][2];
  #pragma unroll
  for (int mt = 0; mt < 4; ++mt) {
    Ah[0][mt] = *(const half8*)(vhi + offA[mt]);
    Al[0][mt] = *(const half8*)(vlo + offA[mt]);
  }
  #pragma unroll
  for (int nt = 0; nt < 2; ++nt) {
    Bh[0][nt] = *(const half8*)(thi + offB[nt]);
    Bl[0][nt] = *(const half8*)(tlo + offB[nt]);
  }

  #pragma unroll
  for (int k = 0; k < 16; ++k) {
    const int c = k & 1, n = c ^ 1;
    if (k < 15) {
      const int ko = (k + 1) * 16;
      #pragma unroll
      for (int mt = 0; mt < 4; ++mt) {
        Ah[n][mt] = *(const half8*)(vhi + offA[mt] + ko);
        Al[n][mt] = *(const half8*)(vlo + offA[mt] + ko);
      }
      #pragma unroll
      for (int nt = 0; nt < 2; ++nt) {
        Bh[n][nt] = *(const half8*)(thi + offB[nt] + ko);
        Bl[n][nt] = *(const half8*)(tlo + offB[nt] + ko);
      }
    }
    // term-major order: consecutive MFMAs hit different accumulators (ILP)
    #pragma unroll
    for (int mt = 0; mt < 4; ++mt)
      #pragma unroll
      for (int nt = 0; nt < 2; ++nt)
        acc[mt][nt] = __builtin_amdgcn_mfma_f32_32x32x16_f16(Al[c][mt], Bh[c][nt], acc[mt][nt], 0, 0, 0);
    #pragma unroll
    for (int mt = 0; mt < 4; ++mt)
      #pragma unroll
      for (int nt = 0; nt < 2; ++nt)
        acc[mt][nt] = __builtin_amdgcn_mfma_f32_32x32x16_f16(Ah[c][mt], Bl[c][nt], acc[mt][nt], 0, 0, 0);
    #pragma unroll
    for (int mt = 0; mt < 4; ++mt)
      #pragma unroll
      for (int nt = 0; nt < 2; ++nt)
        acc[mt][nt] = __builtin_amdgcn_mfma_f32_32x32x16_f16(Ah[c][mt], Bh[c][nt], acc[mt][nt], 0, 0, 0);
  }

  // ---- epilogue (layout verified in R2): col=lane&31, row=(reg&3)+8*(reg>>2)+4*(lane>>5) ----
  sdi[tid] = diag[i0 + tid];
  if (tid < 128) sdj[tid] = diag[j0 + tid];
  __syncthreads();

  float vt = 0.f, tv = 0.f;
  const int h    = lane >> 5;
  const int colL = lane & 31;
  #pragma unroll
  for (int mt = 0; mt < 4; ++mt) {
    const int rbase = (w >> 1) * 128 + mt * 32;
    #pragma unroll
    for (int reg = 0; reg < 16; ++reg) {
      const int r  = (reg & 3) + 8 * (reg >> 2) + 4 * h;
      const int gi = i0 + rbase + r;
      const float di = sdi[rbase + r];
      unsigned long long b0 = 0, b1 = 0;
      #pragma unroll
      for (int nt = 0; nt < 2; ++nt) {
        const int cc = (w & 1) * 64 + nt * 32 + colL;
        const int gj = j0 + cc;
        const float s  = acc[mt][nt][reg];
        const float dj = sdj[cc];
        const bool ne = (gi != gj);
        if (ne) {
          vt += fmaxf(0.f, MARGIN - di + s);
          tv += fmaxf(0.f, MARGIN - dj + s);
        }
        const unsigned long long bb = __ballot(ne && (s > di));
        if (nt == 0) b0 = bb; else b1 = bb;
      }
      if (colL == 0) {
        const int cnt = h ? (int)(__popcll(b0 >> 32) + __popcll(b1 >> 32))
                          : (int)(__popcll(b0 & 0xFFFFFFFFull) + __popcll(b1 & 0xFFFFFFFFull));
        atomicAdd(&rank[gi], cnt);
      }
    }
  }
  #pragma unroll
  for (int off = 32; off; off >>= 1) {
    vt += __shfl_down(vt, off);
    tv += __shfl_down(tv, off);
  }
  if (lane == 0) {
    atomicAdd(&sums[0], vt);
    atomicAdd(&sums[1], tv);
  }
}

// ================= PATH B (fallback, R2-verified): LDS staging =================

__global__ __launch_bounds__(256) void diag_kernel(
    const float* __restrict__ v, const float* __restrict__ t,
    float* __restrict__ diag, int* __restrict__ rank, float* __restrict__ sums) {
  const int wv   = threadIdx.x >> 6;
  const int lane = threadIdx.x & 63;
  const int row  = blockIdx.x * 4 + wv;
  const float4 a = ((const float4*)(v + (size_t)row * DDIM))[lane];
  const float4 b = ((const float4*)(t + (size_t)row * DDIM))[lane];
  float s = a.x*b.x + a.y*b.y + a.z*b.z + a.w*b.w;
  #pragma unroll
  for (int off = 32; off; off >>= 1) s += __shfl_down(s, off);
  if (lane == 0) { diag[row] = s; rank[row] = 0; }
  if (blockIdx.x == 0 && threadIdx.x < 2) sums[threadIdx.x] = 0.f;
}

__device__ inline void stage4(_Float16* __restrict__ dhi, _Float16* __restrict__ dlo,
                              const float4 x) {
  half4 h, l;
  h.x = (_Float16)x.x; l.x = (_Float16)(x.x - (float)h.x);
  h.y = (_Float16)x.y; l.y = (_Float16)(x.y - (float)h.y);
  h.z = (_Float16)x.z; l.z = (_Float16)(x.z - (float)h.z);
  h.w = (_Float16)x.w; l.w = (_Float16)(x.w - (float)h.w);
  *(half4*)dhi = h;
  *(half4*)dlo = l;
}

__global__ __launch_bounds__(256, 2) void main_kernel(
    const float* __restrict__ v, const float* __restrict__ t,
    const float* __restrict__ diag, float* __restrict__ sums,
    int* __restrict__ rank) {
  __shared__ __align__(16) _Float16 Ahi[256 * 40];
  __shared__ __align__(16) _Float16 Alo[256 * 40];
  __shared__ __align__(16) _Float16 Bhi[128 * 40];
  __shared__ __align__(16) _Float16 Blo[128 * 40];
  __shared__ float sdi[256];
  __shared__ float sdj[128];

  const int tid  = threadIdx.x;
  const int w    = tid >> 6;
  const int lane = tid & 63;
  const int i0   = blockIdx.y * 256;
  const int j0   = blockIdx.x * 128;

  sdi[tid] = diag[i0 + tid];
  if (tid < 128) sdj[tid] = diag[j0 + tid];

  floatx16 acc[4][2];
  #pragma unroll
  for (int mt = 0; mt < 4; ++mt)
    #pragma unroll
    for (int nt = 0; nt < 2; ++nt)
      #pragma unroll
      for (int r = 0; r < 16; ++r) acc[mt][nt][r] = 0.f;

  const int srow = tid >> 3;
  const int skc  = (tid & 7) * 4;
  const float* vp = v + (size_t)(i0 + srow) * DDIM + skc;
  const float* tp = t + (size_t)(j0 + srow) * DDIM + skc;

  float4 pa[8], pb[4];
  #pragma unroll
  for (int p = 0; p < 8; ++p) pa[p] = *(const float4*)(vp + (size_t)p * 32 * DDIM);
  #pragma unroll
  for (int p = 0; p < 4; ++p) pb[p] = *(const float4*)(tp + (size_t)p * 32 * DDIM);

  const int mrow  = lane & 31;
  const int khalf = (lane >> 5) * 8;
  const int abase = ((w >> 1) * 128 + mrow) * 40 + khalf;
  const int bbase = ((w & 1) * 64 + mrow) * 40 + khalf;

  for (int s = 0; s < 8; ++s) {
    __syncthreads();
    #pragma unroll
    for (int p = 0; p < 8; ++p)
      stage4(&Ahi[(srow + p * 32) * 40 + skc], &Alo[(srow + p * 32) * 40 + skc], pa[p]);
    #pragma unroll
    for (int p = 0; p < 4; ++p)
      stage4(&Bhi[(srow + p * 32) * 40 + skc], &Blo[(srow + p * 32) * 40 + skc], pb[p]);
    __syncthreads();

    if (s < 7) {
      #pragma unroll
      for (int p = 0; p < 8; ++p)
        pa[p] = *(const float4*)(vp + (size_t)p * 32 * DDIM + (s + 1) * 32);
      #pragma unroll
      for (int p = 0; p < 4; ++p)
        pb[p] = *(const float4*)(tp + (size_t)p * 32 * DDIM + (s + 1) * 32);
    }

    #pragma unroll
    for (int ks = 0; ks < 2; ++ks) {
      half8 bh[2], bl[2];
      #pragma unroll
      for (int nt = 0; nt < 2; ++nt) {
        bh[nt] = *(const half8*)&Bhi[bbase + nt * 32 * 40 + ks * 16];
        bl[nt] = *(const half8*)&Blo[bbase + nt * 32 * 40 + ks * 16];
      }
      #pragma unroll
      for (int mt = 0; mt < 4; ++mt) {
        const half8 ah = *(const half8*)&Ahi[abase + mt * 32 * 40 + ks * 16];
        const half8 al = *(const half8*)&Alo[abase + mt * 32 * 40 + ks * 16];
        #pragma unroll
        for (int nt = 0; nt < 2; ++nt) {
          acc[mt][nt] = __builtin_amdgcn_mfma_f32_32x32x16_f16(al, bh[nt], acc[mt][nt], 0, 0, 0);
          acc[mt][nt] = __builtin_amdgcn_mfma_f32_32x32x16_f16(ah, bl[nt], acc[mt][nt], 0, 0, 0);
          acc[mt][nt] = __builtin_amdgcn_mfma_f32_32x32x16_f16(ah, bh[nt], acc[mt][nt], 0, 0, 0);
        }
      }
    }
  }

  float vt = 0.f, tv = 0.f;
  const int h    = lane >> 5;
  const int colL = lane & 31;
  #pragma unroll
  for (int mt = 0; mt < 4; ++mt) {
    const int rbase = (w >> 1) * 128 + mt * 32;
    #pragma unroll
    for (int reg = 0; reg < 16; ++reg) {
      const int r  = (reg & 3) + 8 * (reg >> 2) + 4 * h;
      const int gi = i0 + rbase + r;
      const float di = sdi[rbase + r];
      unsigned long long b0 = 0, b1 = 0;
      #pragma unroll
      for (int nt = 0; nt < 2; ++nt) {
        const int cc = (w & 1) * 64 + nt * 32 + colL;
        const int gj = j0 + cc;
        const float s  = acc[mt][nt][reg];
        const float dj = sdj[cc];
        const bool ne = (gi != gj);
        if (ne) {
          vt += fmaxf(0.f, MARGIN - di + s);
          tv += fmaxf(0.f, MARGIN - dj + s);
        }
        const unsigned long long bb = __ballot(ne && (s > di));
        if (nt == 0) b0 = bb; else b1 = bb;
      }
      if (colL == 0) {
        const int cnt = h ? (int)(__popcll(b0 >> 32) + __popcll(b1 >> 32))
                          : (int)(__popcll(b0 & 0xFFFFFFFFull) + __popcll(b1 & 0xFFFFFFFFull));
        atomicAdd(&rank[gi], cnt);
      }
    }
  }
  #pragma unroll
  for (int off = 32; off; off >>= 1) {
    vt += __shfl_down(vt, off);
    tv += __shfl_down(tv, off);
  }
  if (lane == 0) {
    atomicAdd(&sums[0], vt);
    atomicAdd(&sums[1], tv);
  }
}

// ---------------- Kernel C: final reduction -> 6 outputs ----------------
__global__ __launch_bounds__(256) void final_kernel(
    const float* __restrict__ sums, const int* __restrict__ rank,
    float* __restrict__ out) {
  __shared__ int s1[4], s5[4], s10[4], ssum[4];
  const int tid = threadIdx.x;
  int c1 = 0, c5 = 0, c10 = 0, cs = 0;
  for (int i = tid; i < NROWS; i += 256) {
    const int r = rank[i];
    c1  += (r < 1);
    c5  += (r < 5);
    c10 += (r < 10);
    cs  += r;
  }
  #pragma unroll
  for (int off = 32; off; off >>= 1) {
    c1  += __shfl_down(c1, off);
    c5  += __shfl_down(c5, off);
    c10 += __shfl_down(c10, off);
    cs  += __shfl_down(cs, off);
  }
  const int w = tid >> 6;
  if ((tid & 63) == 0) { s1[w] = c1; s5[w] = c5; s10[w] = c10; ssum[w] = cs; }
  __syncthreads();
  if (tid == 0) {
    int a1 = 0, a5 = 0, a10 = 0, as = 0;
    for (int k = 0; k < 4; ++k) { a1 += s1[k]; a5 += s5[k]; a10 += s10[k]; as += ssum[k]; }
    const float denom = 4096.0f * 4095.0f;
    out[0] = sums[0] / denom;
    out[1] = sums[1] / denom;
    out[2] = a1  / 4096.0f;
    out[3] = a5  / 4096.0f;
    out[4] = a10 / 4096.0f;
    out[5] = (float)as / 4096.0f;
  }
}

extern "C" void kernel_launch(void* const* d_in, const int* in_sizes, int n_in,
                              void* d_out, int out_size, void* d_ws, size_t ws_size,
                              hipStream_t stream) {
  const float* v = (const float*)d_in[0];
  const float* t = (const float*)d_in[1];
  float* out = (float*)d_out;

  const size_t HALF_ARR = (size_t)NROWS * DDIM * sizeof(_Float16);  // 2 MB
  const size_t NEED = 4 * HALF_ARR + 2 * (size_t)NROWS * 4 + 64;

  if (ws_size >= NEED) {
    _Float16* vhi = (_Float16*)d_ws;
    _Float16* vlo = (_Float16*)((char*)d_ws + HALF_ARR);
    _Float16* thi = (_Float16*)((char*)d_ws + 2 * HALF_ARR);
    _Float16* tlo = (_Float16*)((char*)d_ws + 3 * HALF_ARR);
    float* diag = (float*)((char*)d_ws + 4 * HALF_ARR);
    int*   rank = (int*)((char*)d_ws + 4 * HALF_ARR + NROWS * 4);
    float* sums = (float*)((char*)d_ws + 4 * HALF_ARR + 2 * (size_t)NROWS * 4);

    hipLaunchKernelGGL(convert_diag_kernel, dim3(NROWS / 4), dim3(256), 0, stream,
                       v, t, vhi, vlo, thi, tlo, diag, rank, sums);
    hipLaunchKernelGGL(main_mfma, dim3(512), dim3(256), 0, stream,
                       vhi, vlo, thi, tlo, diag, sums, rank);
    hipLaunchKernelGGL(final_kernel, dim3(1), dim3(256), 0, stream, sums, rank, out);
  } else {
    float* diag = (float*)d_ws;
    int*   rank = (int*)((char*)d_ws + NROWS * sizeof(float));
    float* sums = (float*)((char*)d_ws + 2 * (size_t)NROWS * sizeof(float));

    hipLaunchKernelGGL(diag_kernel, dim3(NROWS / 4), dim3(256), 0, stream,
                       v, t, diag, rank, sums);
    hipLaunchKernelGGL(main_kernel, dim3(32, 16), dim3(256), 0, stream,
                       v, t, diag, sums, rank);
    hipLaunchKernelGGL(final_kernel, dim3(1), dim3(256), 0, stream, sums, rank, out);
  }
}